// Round 3
// baseline (142.332 us; speedup 1.0000x reference)
//
#include <hip/hip_runtime.h>
#include <stddef.h>

#define IMG_N 4096

// LDS layout (float offsets), total 10,192 floats = 40,768 B -> rounds to
// 40,960 B -> exactly 4 blocks/CU (160 KiB), 4 x 512 thr = 2048 = thread cap.
// Level-1 subbands: 40x40 @ stride 42. Level-2: 20x20 @ stride 20.
// Level-3: 10x10 @ stride 10. HH1C/LL1P: 32x32 @ stride 36. LL2P: 16x16 @ 20.
// Alias: LL1P lives in the LL1 slot (LL1 dead after DWT2/phase P2; LL1P
// written in P5 — barrier B2 separates). Everything else has its own slot
// because phases P3..P5 run with NO block barrier between them.
#define S_LH1   0        // 1680
#define S_HL1   1680     // 1680
#define S_HH1   3360     // 1680
#define S_LL1   5040     // 1680  (aliased by LL1P, 32x36=1152, in P5)
#define S_HH1C  6720     // 1152
#define S_LL2   7872     // 400
#define S_LH2   8272     // 400
#define S_HL2   8672     // 400
#define S_HH2   9072     // 400
#define S_LL2P  9472     // 320
#define S_LL3   9792     // 100
#define S_LH3   9892     // 100
#define S_HL3   9992     // 100
#define S_HH3   10092    // 100
#define S_TOTAL 10192

#define S_LL1P  (S_LL1)

__global__ __launch_bounds__(512, 8) void haar_fused(
    const float* __restrict__ x,
    const float* __restrict__ w3, const float* __restrict__ b3,
    const float* __restrict__ w5, const float* __restrict__ b5,
    const float* __restrict__ w7, const float* __restrict__ b7,
    float* __restrict__ out)
{
    __shared__ __align__(16) float sm[S_TOTAL];
    const int tid = threadIdx.x;
    const int bx = blockIdx.x, by = blockIdx.y;
    const int R0 = by * 64, C0 = bx * 64;

    float* LH1 = sm + S_LH1;                // stride 42, 40x40
    float* HL1 = sm + S_HL1;
    float* HH1 = sm + S_HH1;
    float* LL1 = sm + S_LL1;
    float* HH1C = sm + S_HH1C;              // stride 36, 32x32
    float* LL2 = sm + S_LL2;                // stride 20, 20x20
    float* LH2 = sm + S_LH2;
    float* HL2 = sm + S_HL2;
    float* HH2 = sm + S_HH2;
    float* LL2P = sm + S_LL2P;              // stride 20, 16x16
    float* LL3 = sm + S_LL3;                // stride 10, 10x10
    float* LH3 = sm + S_LH3;
    float* HL3 = sm + S_HL3;
    float* HH3 = sm + S_HH3;
    float* LL1P = sm + S_LL1P;              // stride 36, 32x32

    // ==== P1: fused global load + level-1 DWT: 80x80 px -> 40x40 coeffs ====
    const bool interior = (by >= 1) && (by <= 62) && (bx >= 1) && (bx <= 62);
    if (interior) {
        const float* src = x + (size_t)(R0 - 8) * IMG_N + (C0 - 8);
        for (int idx = tid; idx < 800; idx += 512) {
            int u = idx / 20, v2 = (idx % 20) * 2;
            const float* p = src + (size_t)(2 * u) * IMG_N + 2 * v2;
            float4 t = *(const float4*)(p);
            float4 b = *(const float4*)(p + IMG_N);
            int o = u * 42 + v2;
            *(float2*)(LL1 + o) = make_float2((t.x + t.y + b.x + b.y) * 0.5f,
                                              (t.z + t.w + b.z + b.w) * 0.5f);
            *(float2*)(LH1 + o) = make_float2((t.x + t.y - b.x - b.y) * 0.5f,
                                              (t.z + t.w - b.z - b.w) * 0.5f);
            *(float2*)(HL1 + o) = make_float2((t.x - t.y + b.x - b.y) * 0.5f,
                                              (t.z - t.w + b.z - b.w) * 0.5f);
            *(float2*)(HH1 + o) = make_float2((t.x - t.y - b.x + b.y) * 0.5f,
                                              (t.z - t.w - b.z + b.w) * 0.5f);
        }
    } else {
        for (int idx = tid; idx < 800; idx += 512) {
            int u = idx / 20, v2 = (idx % 20) * 2;
            int gr0 = R0 - 8 + 2 * u, gr1 = gr0 + 1;
            int gc = C0 - 8 + 2 * v2;
            bool r0v = (gr0 >= 0 && gr0 < IMG_N), r1v = (gr1 >= 0 && gr1 < IMG_N);
            float tv[4], bv[4];
            #pragma unroll
            for (int k = 0; k < 4; ++k) {
                int g = gc + k;
                bool cv = (g >= 0 && g < IMG_N);
                tv[k] = (r0v && cv) ? x[(size_t)gr0 * IMG_N + g] : 0.0f;
                bv[k] = (r1v && cv) ? x[(size_t)gr1 * IMG_N + g] : 0.0f;
            }
            int o = u * 42 + v2;
            *(float2*)(LL1 + o) = make_float2((tv[0] + tv[1] + bv[0] + bv[1]) * 0.5f,
                                              (tv[2] + tv[3] + bv[2] + bv[3]) * 0.5f);
            *(float2*)(LH1 + o) = make_float2((tv[0] + tv[1] - bv[0] - bv[1]) * 0.5f,
                                              (tv[2] + tv[3] - bv[2] - bv[3]) * 0.5f);
            *(float2*)(HL1 + o) = make_float2((tv[0] - tv[1] + bv[0] - bv[1]) * 0.5f,
                                              (tv[2] - tv[3] + bv[2] - bv[3]) * 0.5f);
            *(float2*)(HH1 + o) = make_float2((tv[0] - tv[1] - bv[0] + bv[1]) * 0.5f,
                                              (tv[2] - tv[3] - bv[2] + bv[3]) * 0.5f);
        }
    }
    __syncthreads();   // B1

    // ==== P2: conv7 on HH1 (waves 0-3) CONCURRENT with DWT2 (waves 4-7) ====
    if (tid < 256) {
        // conv7, 32x32 outputs, 1x4 strip per thread; local = in-tile + 4
        const int i = tid >> 3;
        const int j0 = (tid & 7) << 2;
        const float bias = b7[0];
        float a0 = bias, a1 = bias, a2 = bias, a3 = bias;
        #pragma unroll
        for (int dy = 0; dy < 7; ++dy) {
            const float* row = HH1 + (i + dy + 1) * 42 + (j0 + 1);
            const float* wr = w7 + dy * 7;
            float r0 = row[0], r1 = row[1], r2 = row[2], r3 = row[3], r4 = row[4],
                  r5 = row[5], r6 = row[6], r7 = row[7], r8 = row[8], r9 = row[9];
            float q0 = wr[0], q1 = wr[1], q2 = wr[2], q3 = wr[3], q4 = wr[4],
                  q5 = wr[5], q6 = wr[6];
            a0 += q0*r0 + q1*r1 + q2*r2 + q3*r3 + q4*r4 + q5*r5 + q6*r6;
            a1 += q0*r1 + q1*r2 + q2*r3 + q3*r4 + q4*r5 + q5*r6 + q6*r7;
            a2 += q0*r2 + q1*r3 + q2*r4 + q3*r5 + q4*r6 + q5*r7 + q6*r8;
            a3 += q0*r3 + q1*r4 + q2*r5 + q3*r6 + q4*r7 + q5*r8 + q6*r9;
        }
        *(float4*)(HH1C + i * 36 + j0) = make_float4(a0, a1, a2, a3);
    } else {
        // DWT2: LL1 (40x40, stride 42) -> 20x20 (stride 20)
        int t = tid - 256;
        if (t < 200) {
            int u = t / 10, v2 = (t % 10) * 2;
            float4 tt = *(const float4*)(LL1 + (2 * u) * 42 + 2 * v2);
            float4 bb = *(const float4*)(LL1 + (2 * u + 1) * 42 + 2 * v2);
            int o = u * 20 + v2;
            *(float2*)(LL2 + o) = make_float2((tt.x + tt.y + bb.x + bb.y) * 0.5f,
                                              (tt.z + tt.w + bb.z + bb.w) * 0.5f);
            *(float2*)(LH2 + o) = make_float2((tt.x + tt.y - bb.x - bb.y) * 0.5f,
                                              (tt.z + tt.w - bb.z - bb.w) * 0.5f);
            *(float2*)(HL2 + o) = make_float2((tt.x - tt.y + bb.x - bb.y) * 0.5f,
                                              (tt.z - tt.w + bb.z - bb.w) * 0.5f);
            *(float2*)(HH2 + o) = make_float2((tt.x - tt.y - bb.x + bb.y) * 0.5f,
                                              (tt.z - tt.w - bb.z + bb.w) * 0.5f);
        }
    }
    __syncthreads();   // B2

    // ==== P3: DWT3, wave-redundant (every wave computes all 50 items) ====
    {
        int lane = tid & 63;
        if (lane < 50) {
            int u = lane / 5, v2 = (lane % 5) * 2;
            float4 tt = *(const float4*)(LL2 + (2 * u) * 20 + 2 * v2);
            float4 bb = *(const float4*)(LL2 + (2 * u + 1) * 20 + 2 * v2);
            int o = u * 10 + v2;
            *(float2*)(LL3 + o) = make_float2((tt.x + tt.y + bb.x + bb.y) * 0.5f,
                                              (tt.z + tt.w + bb.z + bb.w) * 0.5f);
            *(float2*)(LH3 + o) = make_float2((tt.x + tt.y - bb.x - bb.y) * 0.5f,
                                              (tt.z + tt.w - bb.z - bb.w) * 0.5f);
            *(float2*)(HL3 + o) = make_float2((tt.x - tt.y + bb.x - bb.y) * 0.5f,
                                              (tt.z - tt.w + bb.z - bb.w) * 0.5f);
            *(float2*)(HH3 + o) = make_float2((tt.x - tt.y - bb.x + bb.y) * 0.5f,
                                              (tt.z - tt.w - bb.z + bb.w) * 0.5f);
        }
        // in-wave fence: own wave's LDS writes visible to own wave's reads
        __builtin_amdgcn_wave_barrier();
        __builtin_amdgcn_s_waitcnt(0);
    }

    // ==== P4: IDWT3 with conv3 fused, wave-redundant (128 items/wave) ====
    {
        const float b3c = b3[0];
        #pragma unroll
        for (int k = 0; k < 2; ++k) {
            int item = (tid & 63) + 64 * k;
            int p = item >> 3, c = item & 7;     // out-pair row p (16), col c (8)
            int r = p >> 1;
            float sr = (p & 1) ? -1.0f : 1.0f;
            // conv3 at in-tile (r,c): HH3 local rows r..r+2, cols c..c+2
            float hh = b3c;
            #pragma unroll
            for (int dy = 0; dy < 3; ++dy) {
                const float* row = HH3 + (r + dy) * 10 + c;
                const float* wr = w3 + dy * 3;
                hh += wr[0]*row[0] + wr[1]*row[1] + wr[2]*row[2];
            }
            int li = (r + 1) * 10 + (c + 1);
            float lo = LL3[li] + sr * LH3[li];
            float hi = HL3[li] + sr * hh;
            *(float2*)(LL2P + p * 20 + 2 * c) =
                make_float2((lo + hi) * 0.5f, (lo - hi) * 0.5f);
        }
        __builtin_amdgcn_wave_barrier();
        __builtin_amdgcn_s_waitcnt(0);
    }

    // ==== P5: IDWT2 with conv5 fused (512 items, 1/thread) ====
    {
        const float b5c = b5[0];
        int p = tid >> 4, c = tid & 15;          // out-pair row p (32), col c (16)
        int r = p >> 1;
        float sr = (p & 1) ? -1.0f : 1.0f;
        // conv5 at in-tile (r,c): HH2 local rows r..r+4, cols c..c+4
        float hh = b5c;
        #pragma unroll
        for (int dy = 0; dy < 5; ++dy) {
            const float* row = HH2 + (r + dy) * 20 + c;
            const float* wr = w5 + dy * 5;
            hh += wr[0]*row[0] + wr[1]*row[1] + wr[2]*row[2] + wr[3]*row[3]
                + wr[4]*row[4];
        }
        int li = (r + 2) * 20 + (c + 2);
        float lo = LL2P[r * 20 + c] + sr * LH2[li];
        float hi = HL2[li] + sr * hh;
        *(float2*)(LL1P + p * 36 + 2 * c) =
            make_float2((lo + hi) * 0.5f, (lo - hi) * 0.5f);
    }
    __syncthreads();   // B3

    // ==== P6: IDWT1 -> out (64x64), float4 stores (2 items/thread) ====
    for (int idx = tid; idx < 1024; idx += 512) {
        const int p = idx >> 4;
        const int c2 = (idx & 15) * 2;
        const int r = p >> 1;
        const float sr = (p & 1) ? -1.0f : 1.0f;
        const int li = (r + 4) * 42 + (c2 + 4);
        const int ci = r * 36 + c2;
        float lo0 = LL1P[ci]     + sr * LH1[li];
        float hi0 = HL1[li]      + sr * HH1C[ci];
        float lo1 = LL1P[ci + 1] + sr * LH1[li + 1];
        float hi1 = HL1[li + 1]  + sr * HH1C[ci + 1];
        float4 o = make_float4((lo0 + hi0) * 0.5f, (lo0 - hi0) * 0.5f,
                               (lo1 + hi1) * 0.5f, (lo1 - hi1) * 0.5f);
        *(float4*)(out + (size_t)(R0 + p) * IMG_N + C0 + 2 * c2) = o;
    }
}

extern "C" void kernel_launch(void* const* d_in, const int* in_sizes, int n_in,
                              void* d_out, int out_size, void* d_ws, size_t ws_size,
                              hipStream_t stream) {
    (void)in_sizes; (void)n_in; (void)out_size; (void)d_ws; (void)ws_size;
    const float* x  = (const float*)d_in[0];
    const float* w3 = (const float*)d_in[1];
    const float* b3 = (const float*)d_in[2];
    const float* w5 = (const float*)d_in[3];
    const float* b5 = (const float*)d_in[4];
    const float* w7 = (const float*)d_in[5];
    const float* b7 = (const float*)d_in[6];
    float* out = (float*)d_out;

    dim3 grid(IMG_N / 64, IMG_N / 64);     // 64x64 tiles of 64x64 output px
    dim3 block(512);
    haar_fused<<<grid, block, 0, stream>>>(x, w3, b3, w5, b5, w7, b7, out);
}

// Round 4
// 133.383 us; speedup vs baseline: 1.0671x; 1.0671x over previous
//
#include <hip/hip_runtime.h>
#include <stddef.h>

#define IMG_N 4096

typedef float vf4 __attribute__((ext_vector_type(4)));

// LDS layout (float offsets), total 9792 floats = 39,168 B -> 4 blocks/CU.
// Level-1 subbands 40x40 @ stride 44 (16B-aligned rows for b128 access).
// Aliases (phase-disjoint, separated by barriers):
//   HH1 slot dead after P2 (conv7)  -> hosts HH2C + level-3 subbands
//   LL1 slot dead after P2 (DWT2)   -> hosts LL1P + LL2P
#define S_LH1   0        // 1760
#define S_HL1   1760     // 1760
#define S_HH1   3520     // 1760
#define S_LL1   5280     // 1760
#define S_HH1C  7040     // 1152 (32x32 @ stride 36)
#define S_LL2   8192     // 400  (20x20 @ stride 20)
#define S_LH2   8592
#define S_HL2   8992
#define S_HH2   9392
#define S_TOTAL 9792

#define S_HH2C  (S_HH1)          // 320  (16x16 @ stride 20)
#define S_LL3   (S_HH1 + 320)    // 100  (10x10 @ stride 10)
#define S_LH3   (S_HH1 + 420)
#define S_HL3   (S_HH1 + 520)
#define S_HH3   (S_HH1 + 620)
#define S_LL1P  (S_LL1)          // 1152 (32x32 @ stride 36)
#define S_LL2P  (S_LL1 + 1152)   // 320  (16x16 @ stride 20)

__global__ __launch_bounds__(512, 8) void haar_fused(
    const float* __restrict__ x,
    const float* __restrict__ w3, const float* __restrict__ b3,
    const float* __restrict__ w5, const float* __restrict__ b5,
    const float* __restrict__ w7, const float* __restrict__ b7,
    float* __restrict__ out)
{
    __shared__ __align__(16) float sm[S_TOTAL];
    const int tid = threadIdx.x;
    const int bx = blockIdx.x, by = blockIdx.y;
    const int R0 = by * 64, C0 = bx * 64;

    float* LH1 = sm + S_LH1;   float* HL1 = sm + S_HL1;
    float* HH1 = sm + S_HH1;   float* LL1 = sm + S_LL1;
    float* HH1C = sm + S_HH1C;
    float* LL2 = sm + S_LL2;   float* LH2 = sm + S_LH2;
    float* HL2 = sm + S_HL2;   float* HH2 = sm + S_HH2;
    float* HH2C = sm + S_HH2C;
    float* LL3 = sm + S_LL3;   float* LH3 = sm + S_LH3;
    float* HL3 = sm + S_HL3;   float* HH3 = sm + S_HH3;
    float* LL1P = sm + S_LL1P; float* LL2P = sm + S_LL2P;

    // ==== P1: global load + level-1 DWT. 400 items = 40 rows x 10 groups. ====
    // Each item: 2x8 pixel patch (4 f4 loads) -> 4 coeff cols, f4 LDS writes.
    const bool interior = (by >= 1) && (by <= 62) && (bx >= 1) && (bx <= 62);
    if (tid < 400) {
        const int u = tid / 10, g = tid % 10;
        float4 t0, t1, bb0, bb1;
        if (interior) {
            const float* p = x + (size_t)(R0 - 8 + 2 * u) * IMG_N + (C0 - 8 + 8 * g);
            t0  = *(const float4*)(p);
            t1  = *(const float4*)(p + 4);
            bb0 = *(const float4*)(p + IMG_N);
            bb1 = *(const float4*)(p + IMG_N + 4);
        } else {
            const int gr0 = R0 - 8 + 2 * u, gr1 = gr0 + 1;
            const int gc = C0 - 8 + 8 * g;
            const bool r0v = (gr0 >= 0 && gr0 < IMG_N), r1v = (gr1 >= 0 && gr1 < IMG_N);
            float tv[8], bv[8];
            #pragma unroll
            for (int k = 0; k < 8; ++k) {
                int gck = gc + k;
                bool cv = (gck >= 0 && gck < IMG_N);
                tv[k] = (r0v && cv) ? x[(size_t)gr0 * IMG_N + gck] : 0.0f;
                bv[k] = (r1v && cv) ? x[(size_t)gr1 * IMG_N + gck] : 0.0f;
            }
            t0  = make_float4(tv[0], tv[1], tv[2], tv[3]);
            t1  = make_float4(tv[4], tv[5], tv[6], tv[7]);
            bb0 = make_float4(bv[0], bv[1], bv[2], bv[3]);
            bb1 = make_float4(bv[4], bv[5], bv[6], bv[7]);
        }
        float4 llv, lhv, hlv, hhv;
        {
            float a = t0.x, b = t0.y, c = bb0.x, d = bb0.y;
            llv.x = (a + b + c + d) * 0.5f; lhv.x = (a + b - c - d) * 0.5f;
            hlv.x = (a - b + c - d) * 0.5f; hhv.x = (a - b - c + d) * 0.5f;
            a = t0.z; b = t0.w; c = bb0.z; d = bb0.w;
            llv.y = (a + b + c + d) * 0.5f; lhv.y = (a + b - c - d) * 0.5f;
            hlv.y = (a - b + c - d) * 0.5f; hhv.y = (a - b - c + d) * 0.5f;
            a = t1.x; b = t1.y; c = bb1.x; d = bb1.y;
            llv.z = (a + b + c + d) * 0.5f; lhv.z = (a + b - c - d) * 0.5f;
            hlv.z = (a - b + c - d) * 0.5f; hhv.z = (a - b - c + d) * 0.5f;
            a = t1.z; b = t1.w; c = bb1.z; d = bb1.w;
            llv.w = (a + b + c + d) * 0.5f; lhv.w = (a + b - c - d) * 0.5f;
            hlv.w = (a - b + c - d) * 0.5f; hhv.w = (a - b - c + d) * 0.5f;
        }
        const int o = u * 44 + 4 * g;
        *(float4*)(LL1 + o) = llv;  *(float4*)(LH1 + o) = lhv;
        *(float4*)(HL1 + o) = hlv;  *(float4*)(HH1 + o) = hhv;
    }
    __syncthreads();   // B1

    // ==== P2: conv7 (threads 0-255) || DWT2 (threads 256-355) ====
    if (tid < 256) {
        // conv7 on HH1, 32x32 in-tile outputs, 1x4 strip per thread.
        // out col j0+m taps HH1 local cols j0+m+1 .. j0+m+7 -> window [j0, j0+11]
        const int i = tid >> 3;
        const int j0 = (tid & 7) << 2;
        const float bias = b7[0];
        float a0 = bias, a1 = bias, a2 = bias, a3 = bias;
        #pragma unroll
        for (int dy = 0; dy < 7; ++dy) {
            const float* rp = HH1 + (i + dy + 1) * 44 + j0;
            float4 A = *(const float4*)(rp);
            float4 B = *(const float4*)(rp + 4);
            float4 C = *(const float4*)(rp + 8);
            const float* wr = w7 + dy * 7;
            float q0 = wr[0], q1 = wr[1], q2 = wr[2], q3 = wr[3], q4 = wr[4],
                  q5 = wr[5], q6 = wr[6];
            a0 += q0*A.y + q1*A.z + q2*A.w + q3*B.x + q4*B.y + q5*B.z + q6*B.w;
            a1 += q0*A.z + q1*A.w + q2*B.x + q3*B.y + q4*B.z + q5*B.w + q6*C.x;
            a2 += q0*A.w + q1*B.x + q2*B.y + q3*B.z + q4*B.w + q5*C.x + q6*C.y;
            a3 += q0*B.x + q1*B.y + q2*B.z + q3*B.w + q4*C.x + q5*C.y + q6*C.z;
        }
        *(float4*)(HH1C + i * 36 + j0) = make_float4(a0, a1, a2, a3);
    } else if (tid < 356) {
        // DWT2: LL1 (40x40 @44) -> 20x20 @20. 100 items = 20 rows x 5 groups.
        const int t = tid - 256;
        const int u = t / 5, g = t % 5;
        const float* rp = LL1 + (2 * u) * 44 + 8 * g;
        float4 t0 = *(const float4*)(rp),      t1 = *(const float4*)(rp + 4);
        float4 c0 = *(const float4*)(rp + 44), c1 = *(const float4*)(rp + 48);
        float4 llv, lhv, hlv, hhv;
        llv.x = (t0.x + t0.y + c0.x + c0.y) * 0.5f; lhv.x = (t0.x + t0.y - c0.x - c0.y) * 0.5f;
        hlv.x = (t0.x - t0.y + c0.x - c0.y) * 0.5f; hhv.x = (t0.x - t0.y - c0.x + c0.y) * 0.5f;
        llv.y = (t0.z + t0.w + c0.z + c0.w) * 0.5f; lhv.y = (t0.z + t0.w - c0.z - c0.w) * 0.5f;
        hlv.y = (t0.z - t0.w + c0.z - c0.w) * 0.5f; hhv.y = (t0.z - t0.w - c0.z + c0.w) * 0.5f;
        llv.z = (t1.x + t1.y + c1.x + c1.y) * 0.5f; lhv.z = (t1.x + t1.y - c1.x - c1.y) * 0.5f;
        hlv.z = (t1.x - t1.y + c1.x - c1.y) * 0.5f; hhv.z = (t1.x - t1.y - c1.x + c1.y) * 0.5f;
        llv.w = (t1.z + t1.w + c1.z + c1.w) * 0.5f; lhv.w = (t1.z + t1.w - c1.z - c1.w) * 0.5f;
        hlv.w = (t1.z - t1.w + c1.z - c1.w) * 0.5f; hhv.w = (t1.z - t1.w - c1.z + c1.w) * 0.5f;
        const int o = u * 20 + 4 * g;
        *(float4*)(LL2 + o) = llv;  *(float4*)(LH2 + o) = lhv;
        *(float4*)(HL2 + o) = hlv;  *(float4*)(HH2 + o) = hhv;
    }
    __syncthreads();   // B2

    // ==== P3: DWT3 (threads 0-49) || conv5 (threads 64-127) ====
    if (tid < 50) {
        // LL2 (20x20 @20) -> level-3 10x10 @10. 50 items = 10 rows x 5 pairs.
        const int u = tid / 5, v2 = (tid % 5) * 2;
        const float* rp = LL2 + (2 * u) * 20 + 2 * v2;
        float4 t0 = *(const float4*)(rp);
        float4 c0 = *(const float4*)(rp + 20);
        const int o = u * 10 + v2;
        *(float2*)(LL3 + o) = make_float2((t0.x + t0.y + c0.x + c0.y) * 0.5f,
                                          (t0.z + t0.w + c0.z + c0.w) * 0.5f);
        *(float2*)(LH3 + o) = make_float2((t0.x + t0.y - c0.x - c0.y) * 0.5f,
                                          (t0.z + t0.w - c0.z - c0.w) * 0.5f);
        *(float2*)(HL3 + o) = make_float2((t0.x - t0.y + c0.x - c0.y) * 0.5f,
                                          (t0.z - t0.w + c0.z - c0.w) * 0.5f);
        *(float2*)(HH3 + o) = make_float2((t0.x - t0.y - c0.x + c0.y) * 0.5f,
                                          (t0.z - t0.w - c0.z + c0.w) * 0.5f);
    } else if (tid >= 64 && tid < 128) {
        // conv5 on HH2: 16x16 in-tile outputs, 1x4 strips (64 strips).
        // out col j0+m taps cols j0+m .. j0+m+4 -> window [j0, j0+7]
        const int s = tid - 64;
        const int i = s >> 2;
        const int j0 = (s & 3) << 2;
        const float bias = b5[0];
        float a0 = bias, a1 = bias, a2 = bias, a3 = bias;
        #pragma unroll
        for (int dy = 0; dy < 5; ++dy) {
            const float* rp = HH2 + (i + dy) * 20 + j0;
            float4 A = *(const float4*)(rp);
            float4 B = *(const float4*)(rp + 4);
            const float* wr = w5 + dy * 5;
            float q0 = wr[0], q1 = wr[1], q2 = wr[2], q3 = wr[3], q4 = wr[4];
            a0 += q0*A.x + q1*A.y + q2*A.z + q3*A.w + q4*B.x;
            a1 += q0*A.y + q1*A.z + q2*A.w + q3*B.x + q4*B.y;
            a2 += q0*A.z + q1*A.w + q2*B.x + q3*B.y + q4*B.z;
            a3 += q0*A.w + q1*B.x + q2*B.y + q3*B.z + q4*B.w;
        }
        *(float4*)(HH2C + i * 20 + j0) = make_float4(a0, a1, a2, a3);
    }
    __syncthreads();   // B3

    // ==== P4: IDWT3 + conv3 fused (threads 0-127): 16x8 col-pair items ====
    if (tid < 128) {
        const int p = tid >> 3, c = tid & 7;
        const int r = p >> 1;
        const float sr = (p & 1) ? -1.0f : 1.0f;
        float hh = b3[0];
        #pragma unroll
        for (int dy = 0; dy < 3; ++dy) {
            const float* row = HH3 + (r + dy) * 10 + c;
            const float* wr = w3 + dy * 3;
            hh += wr[0]*row[0] + wr[1]*row[1] + wr[2]*row[2];
        }
        const int li = (r + 1) * 10 + (c + 1);
        float lo = LL3[li] + sr * LH3[li];
        float hi = HL3[li] + sr * hh;
        *(float2*)(LL2P + p * 20 + 2 * c) =
            make_float2((lo + hi) * 0.5f, (lo - hi) * 0.5f);
    }
    __syncthreads();   // B4

    // ==== P5: IDWT2 (512 threads): 32x16 col-pair items ====
    {
        const int p = tid >> 4, c = tid & 15;
        const int r = p >> 1;
        const float sr = (p & 1) ? -1.0f : 1.0f;
        const int li = (r + 2) * 20 + (c + 2);
        float lo = LL2P[r * 20 + c] + sr * LH2[li];
        float hi = HL2[li] + sr * HH2C[r * 20 + c];
        *(float2*)(LL1P + p * 36 + 2 * c) =
            make_float2((lo + hi) * 0.5f, (lo - hi) * 0.5f);
    }
    __syncthreads();   // B5

    // ==== P6: IDWT1 -> out (64x64), NT float4 stores. 1024 items / 2 rounds ====
    #pragma unroll
    for (int k = 0; k < 2; ++k) {
        const int idx = tid + 512 * k;
        const int p = idx >> 4;
        const int c2 = (idx & 15) * 2;
        const int r = p >> 1;
        const float sr = (p & 1) ? -1.0f : 1.0f;
        const int li = (r + 4) * 44 + (c2 + 4);
        const int ci = r * 36 + c2;
        float2 llp = *(const float2*)(LL1P + ci);
        float2 lh  = *(const float2*)(LH1 + li);
        float2 hl  = *(const float2*)(HL1 + li);
        float2 hhc = *(const float2*)(HH1C + ci);
        float lo0 = llp.x + sr * lh.x;
        float hi0 = hl.x + sr * hhc.x;
        float lo1 = llp.y + sr * lh.y;
        float hi1 = hl.y + sr * hhc.y;
        vf4 o = { (lo0 + hi0) * 0.5f, (lo0 - hi0) * 0.5f,
                  (lo1 + hi1) * 0.5f, (lo1 - hi1) * 0.5f };
        __builtin_nontemporal_store(
            o, (vf4*)(out + (size_t)(R0 + p) * IMG_N + C0 + 2 * c2));
    }
}

extern "C" void kernel_launch(void* const* d_in, const int* in_sizes, int n_in,
                              void* d_out, int out_size, void* d_ws, size_t ws_size,
                              hipStream_t stream) {
    (void)in_sizes; (void)n_in; (void)out_size; (void)d_ws; (void)ws_size;
    const float* x  = (const float*)d_in[0];
    const float* w3 = (const float*)d_in[1];
    const float* b3 = (const float*)d_in[2];
    const float* w5 = (const float*)d_in[3];
    const float* b5 = (const float*)d_in[4];
    const float* w7 = (const float*)d_in[5];
    const float* b7 = (const float*)d_in[6];
    float* out = (float*)d_out;

    dim3 grid(IMG_N / 64, IMG_N / 64);     // 64x64 tiles of 64x64 output px
    dim3 block(512);
    haar_fused<<<grid, block, 0, stream>>>(x, w3, b3, w5, b5, w7, b7, out);
}